// Round 4
// baseline (120.273 us; speedup 1.0000x reference)
//
#include <hip/hip_runtime.h>
#include <hip/hip_bf16.h>
#include <math.h>

// CMDTLoss: supervised-contrastive loss on FFT'd features.
// Plancherel: Re(FFT(u)·conj(FFT(v))) = D*(u·v), ||FFT(u)|| = sqrt(D)*||u||
// => cosine sim of FFT'd rows == cosine sim of raw rows. The reference
// collapses to: sim = (normalized F F^T)/tau -> masked log-prob reduction.
//
// R4: barrier-free GEMM. One wave per 64x64 upper-tri tile (2080 waves),
// MFMA fragments loaded DIRECTLY from global (global_load_dwordx4) with
// double-buffered registers -- no LDS, no __syncthreads, no vmcnt(0) drain.
// R3's diagnosis: 83% stall from barrier-coupled staging at ~2 blocks/CU.

#define NROWS 4096
#define DDIM  512
#define TW    64               // wave tile (64x64)
#define NBG   (NROWS / TW)     // 64 row-groups
#define NTRI  (NBG * (NBG + 1) / 2)  // 2080 wave-tiles

typedef __attribute__((ext_vector_type(8))) short  short8;   // 8 bf16
typedef __attribute__((ext_vector_type(4))) float  floatx4;  // MFMA acc

__device__ inline unsigned short f2bf(float x) {
    unsigned u = __float_as_uint(x);
    return (unsigned short)((u + 0x7FFFu + ((u >> 16) & 1u)) >> 16);
}

// Butterfly sum across each 16-lane group; full-rate v_add_f32_dpp.
__device__ inline float dpp_add16(float v) {
    v += __int_as_float(__builtin_amdgcn_update_dpp(
        0, __float_as_int(v), 0xB1, 0xF, 0xF, true));   // quad_perm xor1
    v += __int_as_float(__builtin_amdgcn_update_dpp(
        0, __float_as_int(v), 0x4E, 0xF, 0xF, true));   // quad_perm xor2
    v += __int_as_float(__builtin_amdgcn_update_dpp(
        0, __float_as_int(v), 0x141, 0xF, 0xF, true));  // row_half_mirror
    v += __int_as_float(__builtin_amdgcn_update_dpp(
        0, __float_as_int(v), 0x140, 0xF, 0xF, true));  // row_mirror
    return v;
}

// One pass over F: bf16 convert, row invn (sqrt(1/tau) folded), zero S/P;
// block 0 builds the label histogram.
__global__ __launch_bounds__(256) void prep_kernel(
    const float* __restrict__ F, const int* __restrict__ labels,
    unsigned short* __restrict__ Fb, float* __restrict__ invn,
    float* __restrict__ S, float* __restrict__ P, int* __restrict__ hist) {
    const int wave = threadIdx.x >> 6, lane = threadIdx.x & 63;
    const int row = blockIdx.x * 4 + wave;
    const float4* p = (const float4*)(F + (size_t)row * DDIM);
    float4 v0 = p[lane];
    float4 v1 = p[lane + 64];
    float s = v0.x * v0.x + v0.y * v0.y + v0.z * v0.z + v0.w * v0.w
            + v1.x * v1.x + v1.y * v1.y + v1.z * v1.z + v1.w * v1.w;
    ushort4 o0 = { f2bf(v0.x), f2bf(v0.y), f2bf(v0.z), f2bf(v0.w) };
    ushort4 o1 = { f2bf(v1.x), f2bf(v1.y), f2bf(v1.z), f2bf(v1.w) };
    ushort4* q = (ushort4*)(Fb + (size_t)row * DDIM);
    q[lane] = o0;
    q[lane + 64] = o1;
#pragma unroll
    for (int m = 1; m < 64; m <<= 1) s += __shfl_xor(s, m, 64);
    if (lane == 0) {
        invn[row] = rsqrtf(s) * 3.16227766017f;  // * sqrt(1/TEMPERATURE)
        S[row] = 0.f;
        P[row] = 0.f;
    }
    if (blockIdx.x == 0) {
        __shared__ int h[128];
        if (threadIdx.x < 128) h[threadIdx.x] = 0;
        __syncthreads();
        for (int i = threadIdx.x; i < NROWS; i += 256)
            atomicAdd(&h[labels[i]], 1);
        __syncthreads();
        if (threadIdx.x < 128) hist[threadIdx.x] = h[threadIdx.x];
    }
}

// Barrier-free symmetric fused GEMM + epilogue. Grid 520 x 256 threads;
// each wave independently owns one upper-tri 64x64 tile.
__global__ __launch_bounds__(256) void fused_direct_kernel(
    const unsigned short* __restrict__ Fb, const float* __restrict__ invn,
    const int* __restrict__ labels,
    float* __restrict__ S, float* __restrict__ P) {
    const int wid = blockIdx.x * 4 + (threadIdx.x >> 6);  // 0..NTRI-1
    const int lane = threadIdx.x & 63;
    const int lrow = lane & 15;
    const int lquad = lane >> 4;

    // upper-tri decode: first index of row bi is bi*NBG - bi*(bi-1)/2
    int bi = (int)((129.0f - sqrtf(16641.0f - 8.0f * (float)wid)) * 0.5f);
    while (bi > 0 && bi * NBG - bi * (bi - 1) / 2 > wid) --bi;
    while ((bi + 1) * NBG - (bi + 1) * bi / 2 <= wid) ++bi;
    const int bj = bi + (wid - (bi * NBG - bi * (bi - 1) / 2));
    const bool diag = (bi == bj);
    const int ib = bi * TW, jb = bj * TW;

    // Fragment base addresses: lane reads 16B at row(lrow), k = lquad*8.
    // Per K-step only the immediate offset changes (k0*2 bytes).
    const unsigned short* baseA = Fb + (size_t)(ib + lrow) * DDIM + lquad * 8;
    const unsigned short* baseB = Fb + (size_t)(jb + lrow) * DDIM + lquad * 8;

    floatx4 acc[4][4];
#pragma unroll
    for (int mi = 0; mi < 4; ++mi)
#pragma unroll
        for (int ni = 0; ni < 4; ++ni) acc[mi][ni] = (floatx4){0.f, 0.f, 0.f, 0.f};

    short8 af[2][4], bf[2][4];
#pragma unroll
    for (int mi = 0; mi < 4; ++mi)
        af[0][mi] = *(const short8*)(baseA + (size_t)mi * 16 * DDIM);
#pragma unroll
    for (int ni = 0; ni < 4; ++ni)
        bf[0][ni] = *(const short8*)(baseB + (size_t)ni * 16 * DDIM);

#pragma unroll
    for (int ks = 0; ks < 16; ++ks) {
        const int cur = ks & 1, nxt = cur ^ 1;
        if (ks < 15) {
            const int ko = (ks + 1) * 32;
#pragma unroll
            for (int mi = 0; mi < 4; ++mi)
                af[nxt][mi] = *(const short8*)(baseA + (size_t)mi * 16 * DDIM + ko);
#pragma unroll
            for (int ni = 0; ni < 4; ++ni)
                bf[nxt][ni] = *(const short8*)(baseB + (size_t)ni * 16 * DDIM + ko);
        }
#pragma unroll
        for (int mi = 0; mi < 4; ++mi)
#pragma unroll
            for (int ni = 0; ni < 4; ++ni)
                acc[mi][ni] = __builtin_amdgcn_mfma_f32_16x16x32_bf16(
                    af[cur][mi], bf[cur][ni], acc[mi][ni], 0, 0, 0);
    }

    // Epilogue. C/D layout: col = lrow, row = lquad*4 + reg.
    float inB[4];
    int lB[4];
#pragma unroll
    for (int ni = 0; ni < 4; ++ni) {
        int j = jb + ni * 16 + lrow;
        inB[ni] = invn[j];
        lB[ni] = labels[j];
    }
    float inA[4][4];
    int lA[4][4];
#pragma unroll
    for (int mi = 0; mi < 4; ++mi)
#pragma unroll
        for (int r = 0; r < 4; ++r) {
            int i = ib + mi * 16 + lquad * 4 + r;
            inA[mi][r] = invn[i];
            lA[mi][r] = labels[i];
        }

    float ecol[4] = {0.f, 0.f, 0.f, 0.f};
    float pcol[4] = {0.f, 0.f, 0.f, 0.f};

#pragma unroll
    for (int mi = 0; mi < 4; ++mi) {
#pragma unroll
        for (int r = 0; r < 4; ++r) {
            const int i = ib + mi * 16 + lquad * 4 + r;
            float es = 0.f, ps = 0.f;
#pragma unroll
            for (int ni = 0; ni < 4; ++ni) {
                const int j = jb + ni * 16 + lrow;
                float sim = acc[mi][ni][r] * inA[mi][r] * inB[ni];
                float e = __expf(sim);
                float pm = (lA[mi][r] == lB[ni]) ? sim : 0.f;
                if (diag && i == j) { e = 0.f; pm = 0.f; }
                es += e; ps += pm;
                ecol[ni] += e; pcol[ni] += pm;
            }
            es = dpp_add16(es);
            ps = dpp_add16(ps);
            if (lrow == 0) {
                atomicAdd(&S[i], es);
                atomicAdd(&P[i], ps);
            }
        }
    }

    if (!diag) {
        // transpose contributions: reduce across lquad (lane bits 4,5)
#pragma unroll
        for (int ni = 0; ni < 4; ++ni) {
            float e = ecol[ni], pq = pcol[ni];
            e += __shfl_xor(e, 16, 64);
            e += __shfl_xor(e, 32, 64);
            pq += __shfl_xor(pq, 16, 64);
            pq += __shfl_xor(pq, 32, 64);
            if (lquad == 0) {
                int j = jb + ni * 16 + lrow;
                atomicAdd(&S[j], e);
                atomicAdd(&P[j], pq);
            }
        }
    }
}

__global__ __launch_bounds__(1024) void final_kernel(
    const float* __restrict__ S, const float* __restrict__ P,
    const int* __restrict__ labels, const int* __restrict__ hist,
    float* __restrict__ out) {
    float local = 0.f;
    for (int i = threadIdx.x; i < NROWS; i += 1024) {
        float cnt = (float)(hist[labels[i]] - 1);
        local += (P[i] - cnt * logf(S[i])) / (cnt + 1e-8f);
    }
#pragma unroll
    for (int m = 1; m < 64; m <<= 1) local += __shfl_xor(local, m, 64);
    __shared__ float red[16];
    int wave = threadIdx.x >> 6;
    if ((threadIdx.x & 63) == 0) red[wave] = local;
    __syncthreads();
    if (threadIdx.x == 0) {
        float s = 0.f;
#pragma unroll
        for (int w = 0; w < 16; ++w) s += red[w];
        out[0] = -s / (float)NROWS;
    }
}

extern "C" void kernel_launch(void* const* d_in, const int* in_sizes, int n_in,
                              void* d_out, int out_size, void* d_ws, size_t ws_size,
                              hipStream_t stream) {
    const float* F = (const float*)d_in[0];
    const int* labels = (const int*)d_in[1];
    float* out = (float*)d_out;

    // ws layout: invn[4096 f] | S[4096 f] | P[4096 f] | hist[128 i] | Fb[4 MB]
    float* invn = (float*)d_ws;
    float* S = invn + NROWS;
    float* P = S + NROWS;
    int* hist = (int*)(P + NROWS);
    unsigned short* Fb = (unsigned short*)(hist + 128);

    prep_kernel<<<dim3(NROWS / 4), dim3(256), 0, stream>>>(
        F, labels, Fb, invn, S, P, hist);
    fused_direct_kernel<<<dim3(NTRI / 4), dim3(256), 0, stream>>>(
        Fb, invn, labels, S, P);
    final_kernel<<<dim3(1), dim3(1024), 0, stream>>>(S, P, labels, hist, out);
}

// Round 5
// 94.615 us; speedup vs baseline: 1.2712x; 1.2712x over previous
//
#include <hip/hip_runtime.h>
#include <hip/hip_bf16.h>
#include <math.h>

// CMDTLoss: supervised-contrastive loss on FFT'd features.
// Plancherel: Re(FFT(u)·conj(FFT(v))) = D*(u·v), ||FFT(u)|| = sqrt(D)*||u||
// => cosine sim of FFT'd rows == cosine sim of raw rows. The reference
// collapses to: sim = (normalized F F^T)/tau -> masked log-prob reduction.
//
// R5: fragment-major relayout. R4 failed because direct MFMA-fragment loads
// have zero consecutive-lane contiguity (lane l -> row(l&15)*1KB) -> each
// load = ~64 serialized transactions (~500 cyc effective). Fix: prep writes
// Fbf[group][kstep][lane] so every fragment load is base + lane*16B -- one
// coalesced 1KB transaction. Barrier-free wave-per-tile GEMM kept from R4,
// prefetch deepened to 3 rotating buffers (2 K-steps ahead).

#define NROWS 4096
#define DDIM  512
#define TW    64                     // wave tile (64x64)
#define NBG   (NROWS / TW)           // 64 row-groups of 64
#define NTRI  (NBG * (NBG + 1) / 2)  // 2080 wave-tiles
#define NGRP  (NROWS / 16)           // 256 fragment row-groups (16 rows)
#define NSTEP (DDIM / 32)            // 16 K-steps

typedef __attribute__((ext_vector_type(8))) short  short8;   // 8 bf16 = 16B
typedef __attribute__((ext_vector_type(4))) float  floatx4;  // MFMA acc

__device__ inline unsigned short f2bf(float x) {
    unsigned u = __float_as_uint(x);
    return (unsigned short)((u + 0x7FFFu + ((u >> 16) & 1u)) >> 16);
}

// Butterfly sum across each 16-lane group; full-rate v_add_f32_dpp.
__device__ inline float dpp_add16(float v) {
    v += __int_as_float(__builtin_amdgcn_update_dpp(
        0, __float_as_int(v), 0xB1, 0xF, 0xF, true));   // quad_perm xor1
    v += __int_as_float(__builtin_amdgcn_update_dpp(
        0, __float_as_int(v), 0x4E, 0xF, 0xF, true));   // quad_perm xor2
    v += __int_as_float(__builtin_amdgcn_update_dpp(
        0, __float_as_int(v), 0x141, 0xF, 0xF, true));  // row_half_mirror
    v += __int_as_float(__builtin_amdgcn_update_dpp(
        0, __float_as_int(v), 0x140, 0xF, 0xF, true));  // row_mirror
    return v;
}

// Prep: bf16 convert into FRAGMENT-MAJOR layout, row norms, zero S/P, hist.
// Block g handles row-group g (16 rows). Fbf unit (16B) index:
//   g*1024 + s*64 + l,  where lane slot l holds row g*16+(l&15),
//   k = s*32 + (l>>4)*8 .. +7.   Thread t writes units t + 256c (c=0..3):
//   consecutive threads -> consecutive 16B units (coalesced stores).
__global__ __launch_bounds__(256) void prep_kernel(
    const float* __restrict__ F, const int* __restrict__ labels,
    unsigned short* __restrict__ Fbf, float* __restrict__ invn,
    float* __restrict__ S, float* __restrict__ P, int* __restrict__ hist) {
    const int g = blockIdx.x;
    const int t = threadIdx.x;
    const int l = t & 63;
    const int row = g * 16 + (l & 15);
    const int kbase = (l >> 4) * 8;
    short8* dst = (short8*)Fbf + (size_t)g * 1024 + t;
    float ss = 0.f;
#pragma unroll
    for (int c = 0; c < 4; ++c) {
        const int s = (t >> 6) + c * 4;  // u = t + 256c -> s = u>>6
        const int k = s * 32 + kbase;
        const float4* src = (const float4*)(F + (size_t)row * DDIM + k);
        float4 v0 = src[0], v1 = src[1];
        ss += v0.x * v0.x + v0.y * v0.y + v0.z * v0.z + v0.w * v0.w
            + v1.x * v1.x + v1.y * v1.y + v1.z * v1.z + v1.w * v1.w;
        short8 o;
        o[0] = (short)f2bf(v0.x); o[1] = (short)f2bf(v0.y);
        o[2] = (short)f2bf(v0.z); o[3] = (short)f2bf(v0.w);
        o[4] = (short)f2bf(v1.x); o[5] = (short)f2bf(v1.y);
        o[6] = (short)f2bf(v1.z); o[7] = (short)f2bf(v1.w);
        dst[c * 256] = o;
    }
    // per-row sumsq: lanes {r, r+16, r+32, r+48} share a row
    ss += __shfl_xor(ss, 16, 64);
    ss += __shfl_xor(ss, 32, 64);
    __shared__ float red[4][16];
    if (l < 16) red[t >> 6][l] = ss;
    __syncthreads();
    if (t < 16) {
        float tot = red[0][t] + red[1][t] + red[2][t] + red[3][t];
        invn[g * 16 + t] = rsqrtf(tot) * 3.16227766017f;  // * sqrt(1/tau)
        S[g * 16 + t] = 0.f;
        P[g * 16 + t] = 0.f;
    }
    if (g == 0) {
        __shared__ int h[128];
        if (t < 128) h[t] = 0;
        __syncthreads();
        for (int i = t; i < NROWS; i += 256) atomicAdd(&h[labels[i]], 1);
        __syncthreads();
        if (t < 128) hist[t] = h[t];
    }
}

// Barrier-free symmetric fused GEMM + epilogue, fragment-major loads.
// Grid 520 x 256; each wave owns one upper-tri 64x64 tile.
__global__ __launch_bounds__(256) void fused_frag_kernel(
    const unsigned short* __restrict__ Fbf, const float* __restrict__ invn,
    const int* __restrict__ labels,
    float* __restrict__ S, float* __restrict__ P) {
    const int wid = blockIdx.x * 4 + (threadIdx.x >> 6);  // 0..NTRI-1
    const int lane = threadIdx.x & 63;
    const int lrow = lane & 15;
    const int lquad = lane >> 4;

    // upper-tri decode: first index of row bi is bi*NBG - bi*(bi-1)/2
    int bi = (int)((129.0f - sqrtf(16641.0f - 8.0f * (float)wid)) * 0.5f);
    while (bi > 0 && bi * NBG - bi * (bi - 1) / 2 > wid) --bi;
    while ((bi + 1) * NBG - (bi + 1) * bi / 2 <= wid) ++bi;
    const int bj = bi + (wid - (bi * NBG - bi * (bi - 1) / 2));
    const bool diag = (bi == bj);
    const int ib = bi * TW, jb = bj * TW;

    // fragment-major bases: unit = group*1024 + s*64 + lane (16B units)
    const short8* FU = (const short8*)Fbf;
    const short8* pA = FU + (size_t)(bi * 4) * 1024 + lane;
    const short8* pB = FU + (size_t)(bj * 4) * 1024 + lane;

    floatx4 acc[4][4];
#pragma unroll
    for (int mi = 0; mi < 4; ++mi)
#pragma unroll
        for (int ni = 0; ni < 4; ++ni) acc[mi][ni] = (floatx4){0.f, 0.f, 0.f, 0.f};

    short8 af[3][4], bf[3][4];
#pragma unroll
    for (int p = 0; p < 2; ++p) {
#pragma unroll
        for (int mi = 0; mi < 4; ++mi) af[p][mi] = pA[mi * 1024 + p * 64];
#pragma unroll
        for (int ni = 0; ni < 4; ++ni) bf[p][ni] = pB[ni * 1024 + p * 64];
    }

#pragma unroll
    for (int ks = 0; ks < NSTEP; ++ks) {
        const int cur = ks % 3;
        if (ks + 2 < NSTEP) {
            const int nb = (ks + 2) % 3;
#pragma unroll
            for (int mi = 0; mi < 4; ++mi)
                af[nb][mi] = pA[mi * 1024 + (ks + 2) * 64];
#pragma unroll
            for (int ni = 0; ni < 4; ++ni)
                bf[nb][ni] = pB[ni * 1024 + (ks + 2) * 64];
        }
#pragma unroll
        for (int mi = 0; mi < 4; ++mi)
#pragma unroll
            for (int ni = 0; ni < 4; ++ni)
                acc[mi][ni] = __builtin_amdgcn_mfma_f32_16x16x32_bf16(
                    af[cur][mi], bf[cur][ni], acc[mi][ni], 0, 0, 0);
    }

    // Epilogue. C/D layout: col = lrow, row = lquad*4 + reg.
    float inB[4];
    int lB[4];
#pragma unroll
    for (int ni = 0; ni < 4; ++ni) {
        int j = jb + ni * 16 + lrow;
        inB[ni] = invn[j];
        lB[ni] = labels[j];
    }
    float inA[4][4];
    int lA[4][4];
#pragma unroll
    for (int mi = 0; mi < 4; ++mi)
#pragma unroll
        for (int r = 0; r < 4; ++r) {
            int i = ib + mi * 16 + lquad * 4 + r;
            inA[mi][r] = invn[i];
            lA[mi][r] = labels[i];
        }

    float ecol[4] = {0.f, 0.f, 0.f, 0.f};
    float pcol[4] = {0.f, 0.f, 0.f, 0.f};

#pragma unroll
    for (int mi = 0; mi < 4; ++mi) {
#pragma unroll
        for (int r = 0; r < 4; ++r) {
            const int i = ib + mi * 16 + lquad * 4 + r;
            float es = 0.f, ps = 0.f;
#pragma unroll
            for (int ni = 0; ni < 4; ++ni) {
                const int j = jb + ni * 16 + lrow;
                float sim = acc[mi][ni][r] * inA[mi][r] * inB[ni];
                float e = __expf(sim);
                float pm = (lA[mi][r] == lB[ni]) ? sim : 0.f;
                if (diag && i == j) { e = 0.f; pm = 0.f; }
                es += e; ps += pm;
                ecol[ni] += e; pcol[ni] += pm;
            }
            es = dpp_add16(es);
            ps = dpp_add16(ps);
            if (lrow == 0) {
                atomicAdd(&S[i], es);
                atomicAdd(&P[i], ps);
            }
        }
    }

    if (!diag) {
        // transpose contributions: reduce across lquad (lane bits 4,5)
#pragma unroll
        for (int ni = 0; ni < 4; ++ni) {
            float e = ecol[ni], pq = pcol[ni];
            e += __shfl_xor(e, 16, 64);
            e += __shfl_xor(e, 32, 64);
            pq += __shfl_xor(pq, 16, 64);
            pq += __shfl_xor(pq, 32, 64);
            if (lquad == 0) {
                int j = jb + ni * 16 + lrow;
                atomicAdd(&S[j], e);
                atomicAdd(&P[j], pq);
            }
        }
    }
}

__global__ __launch_bounds__(1024) void final_kernel(
    const float* __restrict__ S, const float* __restrict__ P,
    const int* __restrict__ labels, const int* __restrict__ hist,
    float* __restrict__ out) {
    float local = 0.f;
    for (int i = threadIdx.x; i < NROWS; i += 1024) {
        float cnt = (float)(hist[labels[i]] - 1);
        local += (P[i] - cnt * logf(S[i])) / (cnt + 1e-8f);
    }
#pragma unroll
    for (int m = 1; m < 64; m <<= 1) local += __shfl_xor(local, m, 64);
    __shared__ float red[16];
    int wave = threadIdx.x >> 6;
    if ((threadIdx.x & 63) == 0) red[wave] = local;
    __syncthreads();
    if (threadIdx.x == 0) {
        float s = 0.f;
#pragma unroll
        for (int w = 0; w < 16; ++w) s += red[w];
        out[0] = -s / (float)NROWS;
    }
}

extern "C" void kernel_launch(void* const* d_in, const int* in_sizes, int n_in,
                              void* d_out, int out_size, void* d_ws, size_t ws_size,
                              hipStream_t stream) {
    const float* F = (const float*)d_in[0];
    const int* labels = (const int*)d_in[1];
    float* out = (float*)d_out;

    // ws layout: Fbf[4MB, 16B-aligned at base] | invn[4096f] | S | P | hist[128i]
    unsigned short* Fbf = (unsigned short*)d_ws;
    float* invn = (float*)(Fbf + (size_t)NROWS * DDIM);
    float* S = invn + NROWS;
    float* P = S + NROWS;
    int* hist = (int*)(P + NROWS);

    prep_kernel<<<dim3(NGRP), dim3(256), 0, stream>>>(
        F, labels, Fbf, invn, S, P, hist);
    fused_frag_kernel<<<dim3(NTRI / 4), dim3(256), 0, stream>>>(
        Fbf, invn, labels, S, P);
    final_kernel<<<dim3(1), dim3(1024), 0, stream>>>(S, P, labels, hist, out);
}